// Round 11
// baseline (100.019 us; speedup 1.0000x reference)
//
#include <hip/hip_runtime.h>

// ScaledDotProductAttention w/ ALiBi + key padding mask. B=1,H=16,S=2048,D=64 fp32.
// R11 == R10 resubmitted (R10 bench was an infra failure: container died twice;
// same signature as R8, whose identical resubmission R9 ran clean).
// R10: double-buffered K/V staging in attn_main -- prefetch tile kt+1's DMA
// before computing tile kt so the compiler's vmcnt(0)-before-barrier drain
// lands AFTER compute (overlap), one barrier per tile instead of two.
// Carried: 3-dispatch structure (R7 showed fused combine's __threadfence =
// per-block L2 writeback on non-coherent XCD L2s is a disaster), bf16
// pre-scaled Q, bf16 partials, no online max (bias in acc init, exp2 domain),
// ALiBi window cut, weighted chunking (<=4 tiles/blk), global_load_lds
// staging of pre-swizzled bf16 K/V^T, packed-u32 P round-trip.

constexpr int   S_LEN  = 2048;
constexpr int   D_DIM  = 64;
constexpr int   H_NUM  = 16;
constexpr int   QT     = 128;            // q rows per block (4 waves x 32)
constexpr int   K_TILE = 64;
constexpr int   NTILE  = S_LEN / K_TILE; // 32
constexpr int   MAXNC  = 8;              // max chunks per head (z-dim)
constexpr int   QB     = S_LEN / QT;     // 16
constexpr int   HC0    = 6;              // first multi-chunk head (h0..h5 have nc==1)
constexpr int   PROWSTR= 36;             // dwords per P row (144B, 16B-mult)
constexpr float SCL    = 0.18033688f;    // 0.125 * log2(e)
constexpr float L2E    = 1.44269504f;
constexpr float MASKED = -50000.0f;      // exp2-domain masked-key sentinel -> exp2 = 0
constexpr float CUTOFF = 40.0f;          // log2-units: bias < -40 => key negligible

typedef short bf16x8 __attribute__((ext_vector_type(8)));
typedef short bf16x4 __attribute__((ext_vector_type(4)));
typedef float f32x4  __attribute__((ext_vector_type(4)));

__device__ inline short f2bf(float f) {
    union { float f; unsigned u; } x; x.f = f;
    return (short)((x.u + 0x7fffu + ((x.u >> 16) & 1u)) >> 16);  // RNE
}

__device__ inline unsigned pack2bf(float a, float b) {
#if __has_builtin(__builtin_amdgcn_cvt_pk_bf16_f32)
    auto p = __builtin_amdgcn_cvt_pk_bf16_f32(a, b);
    unsigned u; __builtin_memcpy(&u, &p, 4); return u;
#else
    return (unsigned)(unsigned short)f2bf(a) | ((unsigned)(unsigned short)f2bf(b) << 16);
#endif
}

__device__ inline float fexp2(float x) {
#if __has_builtin(__builtin_amdgcn_exp2f)
    return __builtin_amdgcn_exp2f(x);
#else
    return exp2f(x);
#endif
}

__device__ inline unsigned permb(unsigned hi, unsigned lo, unsigned sel) {
#if __has_builtin(__builtin_amdgcn_perm)
    return __builtin_amdgcn_perm(hi, lo, sel);
#else
    return (sel == 0x05040100u) ? ((lo & 0xffffu) | (hi << 16))
                                : ((lo >> 16) | (hi & 0xffff0000u));
#endif
}

__device__ inline void load_lds16(const void* g, void* l) {
    __builtin_amdgcn_global_load_lds((const __attribute__((address_space(1))) void*)g,
                                     (__attribute__((address_space(3))) void*)l, 16, 0, 0);
}

// first live tile for head h (identical IEEE expression in all kernels)
__device__ inline int head_t0(int h) {
    const float slope_l2e = exp2f(-0.5f * (float)(h + 1)) * L2E;
    const float kmin = 2047.0f - CUTOFF / slope_l2e;
    return kmin <= 0.0f ? 0 : ((int)kmin) >> 6;
}
// chunks for head h: ceil(live_tiles / 4), capped at MAXNC
__device__ inline int head_nc(int h) {
    const int nt = NTILE - head_t0(h);
    const int nc = (nt + 3) >> 2;
    return nc > MAXNC ? MAXNC : nc;
}

// ---- preprocess: Q -> bf16 pre-scaled; K -> bf16 row-chunk-swizzled;
//      V -> bf16 transposed+swizzled; bias (exp2 units, mask folded). ----
__global__ __launch_bounds__(256)
void preprocess_kernel(const float* __restrict__ Qm, const float* __restrict__ Km,
                       const float* __restrict__ Vm, const void* __restrict__ maskp,
                       short* __restrict__ Qbf, short* __restrict__ Kswz,
                       short* __restrict__ Vswz, float* __restrict__ Bias)
{
    __shared__ int mask_is_i32;
    const int tid = threadIdx.x;
    const int kt = blockIdx.x, h = blockIdx.y;

    // Q tile: rows [kt*64, kt*64+64) of head h -> bf16 * SCL, row-major
    {
        const int row = kt * 64 + (tid >> 2);
        const int col = (tid & 3) << 4;
        const float* src = Qm + ((size_t)h * S_LEN + row) * D_DIM + col;
        short* dst = Qbf + ((size_t)h * S_LEN + row) * D_DIM + col;
        #pragma unroll
        for (int j = 0; j < 2; ++j) {
            float4 a = *(const float4*)(src + j * 8);
            float4 b = *(const float4*)(src + j * 8 + 4);
            unsigned u[4] = { pack2bf(a.x * SCL, a.y * SCL), pack2bf(a.z * SCL, a.w * SCL),
                              pack2bf(b.x * SCL, b.y * SCL), pack2bf(b.z * SCL, b.w * SCL) };
            bf16x8 qp; __builtin_memcpy(&qp, u, 16);
            *(bf16x8*)(dst + j * 8) = qp;
        }
    }

    if (kt < head_t0(h)) return;            // dead K/V tile for this head

    const int kbase = kt * K_TILE;
    const size_t tbase = ((size_t)h * S_LEN + kbase) * D_DIM;
    short* Kd = Kswz + ((size_t)h * NTILE + kt) * 4096;
    short* Vd = Vswz + ((size_t)h * NTILE + kt) * 4096;

    // parallel mask-dtype sniff: first wave, one load + ballot
    if (tid < 64) {
        const unsigned v = ((const unsigned*)maskp)[tid];
        const unsigned long long b = __ballot(v <= 1u);
        if (tid == 0) mask_is_i32 = (b == ~0ULL);
    }

    // K: chunk c of row `key` stored at c ^ (key&7)
    #pragma unroll
    for (int it = 0; it < 2; ++it) {
        const int idx = it * 256 + tid;
        const int key = idx >> 3, c = idx & 7;
        const float* src = Km + tbase + key * 64 + c * 8;
        float4 a = *(const float4*)src;
        float4 b = *(const float4*)(src + 4);
        unsigned u[4] = { pack2bf(a.x, a.y), pack2bf(a.z, a.w),
                          pack2bf(b.x, b.y), pack2bf(b.z, b.w) };
        bf16x8 kp; __builtin_memcpy(&kp, u, 16);
        *(bf16x8*)(Kd + key * 64 + ((c ^ (key & 7)) << 3)) = kp;
    }

    // V: 4x4 register transpose; row d, key-chunk (key>>3)^(d&7)
    {
        const int db = tid >> 4, kb = tid & 15;
        const int d4 = db * 4, key4 = kb * 4;
        float4 vv[4];
        #pragma unroll
        for (int j = 0; j < 4; ++j)
            vv[j] = *(const float4*)(Vm + tbase + (key4 + j) * 64 + d4);
        const float* vp = (const float*)vv;
        #pragma unroll
        for (int jj = 0; jj < 4; ++jj) {
            const int d = d4 + jj;
            bf16x4 ov;
            ov[0] = f2bf(vp[0 * 4 + jj]); ov[1] = f2bf(vp[1 * 4 + jj]);
            ov[2] = f2bf(vp[2 * 4 + jj]); ov[3] = f2bf(vp[3 * 4 + jj]);
            *(bf16x4*)(Vd + d * 64 + (((key4 >> 3) ^ (d & 7)) << 3) + (key4 & 7)) = ov;
        }
    }
    __syncthreads();
    if (tid < K_TILE) {
        const int key = kbase + tid;
        const int mv = mask_is_i32 ? ((const int*)maskp)[key]
                                   : (int)((const unsigned char*)maskp)[key];
        const float slope_l2e = exp2f(-0.5f * (float)(h + 1)) * L2E;
        Bias[h * S_LEN + key] = mv ? slope_l2e * (float)(key - (S_LEN - 1)) : MASKED;
    }
}

// ---- main flash kernel: double-buffered staging, one barrier per tile ----
__global__ __launch_bounds__(256, 3)
void attn_main(const short* __restrict__ Qbf, const short* __restrict__ Kswz,
               const short* __restrict__ Vswz, const float* __restrict__ Bias,
               float* __restrict__ Om, unsigned* __restrict__ Opart,
               float* __restrict__ lp)
{
    __shared__ short    k_lds[2][4096];
    __shared__ short    v_lds[2][4096];
    __shared__ float    bm_lds[2][64];
    __shared__ unsigned p_lds[4][32 * PROWSTR];

    const int tid = threadIdx.x;
    const int wave = tid >> 6, lane = tid & 63;
    const int l16 = lane & 15, quad = lane >> 4;
    const int h = blockIdx.y, qblk = blockIdx.x, c = blockIdx.z;

    const int nc = head_nc(h);
    if (c >= nc) return;                      // dead chunk for this head
    const int t0 = head_t0(h);
    const int nt = NTILE - t0;
    const int tstart = t0 + (c * nt) / nc;
    const int tend   = t0 + ((c + 1) * nt) / nc;   // <= tstart+4

    const unsigned psel = (quad < 2) ? 0x05040100u : 0x07060302u;

    const short* Kh = Kswz + (size_t)h * NTILE * 4096;
    const short* Vh = Vswz + (size_t)h * NTILE * 4096;
    const float* Bh = Bias + h * S_LEN;
    const int go = wave * 2048 + lane * 16;

    // prologue: stage first tile into buffer 0
    {
        const char* kg = (const char*)(Kh + (size_t)tstart * 4096);
        const char* vg = (const char*)(Vh + (size_t)tstart * 4096);
        char* kl = (char*)k_lds[0] + wave * 2048;
        char* vl = (char*)v_lds[0] + wave * 2048;
        load_lds16(kg + go,        kl);
        load_lds16(kg + go + 1024, kl + 1024);
        load_lds16(vg + go,        vl);
        load_lds16(vg + go + 1024, vl + 1024);
        if (tid < 16) {
            float4 b4 = *(const float4*)(Bh + tstart * K_TILE + tid * 4);
            *(float4*)&bm_lds[0][tid * 4] = b4;
        }
    }

    // Q A-frags (already bf16, pre-scaled): 16B contiguous loads
    bf16x8 qfrag[2][2];
    {
        const short* Qh = Qbf + (size_t)h * S_LEN * D_DIM;
        #pragma unroll
        for (int s = 0; s < 2; ++s) {
            const int qrow = qblk * QT + wave * 32 + s * 16 + l16;
            #pragma unroll
            for (int t = 0; t < 2; ++t)
                qfrag[s][t] = *(const bf16x8*)(Qh + (size_t)qrow * D_DIM + t * 32 + quad * 8);
        }
    }

    bf16x8 onesv;
    #pragma unroll
    for (int i = 0; i < 8; ++i) onesv[i] = (short)0x3F80;  // bf16 1.0

    f32x4 o_frag[2][4], l4[2];
    #pragma unroll
    for (int s = 0; s < 2; ++s) {
        #pragma unroll
        for (int cc = 0; cc < 4; ++cc) o_frag[s][cc] = (f32x4){0.f, 0.f, 0.f, 0.f};
        l4[s] = (f32x4){0.f, 0.f, 0.f, 0.f};
    }

    unsigned* pw = p_lds[wave];
    const int swz = l16 & 7;

    __syncthreads();   // drains prologue DMA (compiler emits vmcnt(0) here)

    for (int kt = tstart; kt < tend; ++kt) {
        const int buf = (kt - tstart) & 1;

        // prefetch next tile into the other buffer; its drain happens at the
        // barrier AFTER this tile's compute -> overlapped with compute
        if (kt + 1 < tend) {
            const char* kg = (const char*)(Kh + (size_t)(kt + 1) * 4096);
            const char* vg = (const char*)(Vh + (size_t)(kt + 1) * 4096);
            char* kl = (char*)k_lds[buf ^ 1] + wave * 2048;
            char* vl = (char*)v_lds[buf ^ 1] + wave * 2048;
            load_lds16(kg + go,        kl);
            load_lds16(kg + go + 1024, kl + 1024);
            load_lds16(vg + go,        vl);
            load_lds16(vg + go + 1024, vl + 1024);
            if (tid < 16) {
                float4 b4 = *(const float4*)(Bh + (kt + 1) * K_TILE + tid * 4);
                *(float4*)&bm_lds[buf ^ 1][tid * 4] = b4;
            }
        }

        const short* kb = k_lds[buf];
        const short* vb = v_lds[buf];
        const float* bm = bm_lds[buf];

        // S(+bias) = bias_init + Q K^T
        f32x4 sv[2][4];
        #pragma unroll
        for (int cc = 0; cc < 4; ++cc) {
            const float b = bm[cc * 16 + l16];
            const f32x4 binit = (f32x4){b, b, b, b};
            sv[0][cc] = binit;
            sv[1][cc] = binit;
            #pragma unroll
            for (int t = 0; t < 2; ++t) {
                bf16x8 bfrag = *(const bf16x8*)&kb[(cc * 16 + l16) * 64 + (((t * 4 + quad) ^ swz) << 3)];
                sv[0][cc] = __builtin_amdgcn_mfma_f32_16x16x32_bf16(qfrag[0][t], bfrag, sv[0][cc], 0, 0, 0);
                sv[1][cc] = __builtin_amdgcn_mfma_f32_16x16x32_bf16(qfrag[1][t], bfrag, sv[1][cc], 0, 0, 0);
            }
        }

        // p = exp2(s)  (per-wave P buffer -> no barrier needed around round-trip)
        #pragma unroll
        for (int s = 0; s < 2; ++s) {
            #pragma unroll
            for (int r = 0; r < 4; ++r) {
                const float p0 = fexp2(sv[s][0][r]);
                const float p1 = fexp2(sv[s][1][r]);
                const float p2 = fexp2(sv[s][2][r]);
                const float p3 = fexp2(sv[s][3][r]);
                unsigned* pp = &pw[(s * 16 + quad * 4 + r) * PROWSTR + l16];
                pp[0]  = pack2bf(p0, p1);
                pp[16] = pack2bf(p2, p3);
            }
        }

        // O += P V ; l += P * ones
        #pragma unroll
        for (int t2 = 0; t2 < 2; ++t2) {
            bf16x8 pfrag[2];
            #pragma unroll
            for (int s = 0; s < 2; ++s) {
                const unsigned* pr = &pw[(s * 16 + l16) * PROWSTR + t2 * 16 + (quad & 1) * 8];
                uint4 w0 = *(const uint4*)(pr);
                uint4 w1 = *(const uint4*)(pr + 4);
                unsigned pf[4];
                pf[0] = permb(w0.y, w0.x, psel);
                pf[1] = permb(w0.w, w0.z, psel);
                pf[2] = permb(w1.y, w1.x, psel);
                pf[3] = permb(w1.w, w1.z, psel);
                __builtin_memcpy(&pfrag[s], pf, 16);
            }
            #pragma unroll
            for (int c2 = 0; c2 < 4; ++c2) {
                bf16x8 vfrag = *(const bf16x8*)&vb[(c2 * 16 + l16) * 64 + (((t2 * 4 + quad) ^ swz) << 3)];
                o_frag[0][c2] = __builtin_amdgcn_mfma_f32_16x16x32_bf16(pfrag[0], vfrag, o_frag[0][c2], 0, 0, 0);
                o_frag[1][c2] = __builtin_amdgcn_mfma_f32_16x16x32_bf16(pfrag[1], vfrag, o_frag[1][c2], 0, 0, 0);
            }
            l4[0] = __builtin_amdgcn_mfma_f32_16x16x32_bf16(pfrag[0], onesv, l4[0], 0, 0, 0);
            l4[1] = __builtin_amdgcn_mfma_f32_16x16x32_bf16(pfrag[1], onesv, l4[1], 0, 0, 0);
        }

        __syncthreads();   // one barrier/tile: drains prefetch DMA + P-LDS reuse
    }

    if (nc == 1) {
        // sole chunk: write normalized O directly, skip combine
        float* Oh = Om + (size_t)h * S_LEN * D_DIM;
        const int qrow0 = qblk * QT + wave * 32;
        #pragma unroll
        for (int s = 0; s < 2; ++s) {
            #pragma unroll
            for (int r = 0; r < 4; ++r) {
                const float inv = 1.0f / l4[s][r];
                const int row = qrow0 + s * 16 + quad * 4 + r;
                float* dst = Oh + (size_t)row * D_DIM + l16;
                dst[0]  = o_frag[s][0][r] * inv;
                dst[16] = o_frag[s][1][r] * inv;
                dst[32] = o_frag[s][2][r] * inv;
                dst[48] = o_frag[s][3][r] * inv;
            }
        }
        return;
    }

    // bf16 partial + fp32 l per row-group; slot = h*MAXNC + c
    #pragma unroll
    for (int s = 0; s < 2; ++s) {
        const int g = qblk * 32 + wave * 8 + s * 4 + quad;
        const size_t gbase = (((size_t)h * MAXNC + c) * 512 + g);
        #pragma unroll
        for (int c2 = 0; c2 < 4; ++c2) {
            uint2 pk;
            pk.x = pack2bf(o_frag[s][c2][0], o_frag[s][c2][1]);
            pk.y = pack2bf(o_frag[s][c2][2], o_frag[s][c2][3]);
            *(uint2*)(Opart + (gbase * 64 + c2 * 16 + l16) * 2) = pk;
        }
        if (l16 == 0) *(f32x4*)(lp + gbase * 4) = l4[s];
    }
}

__global__ __launch_bounds__(256)
void attn_combine_kernel(const unsigned* __restrict__ Opart, const float* __restrict__ lp,
                         float* __restrict__ Om)
{
    const int t   = blockIdx.x * 256 + threadIdx.x;   // (H-HC0)*512*64 threads
    const int col = t & 63;
    const int g   = (t >> 6) & 511;
    const int h   = HC0 + (t >> 15);

    const int nc = head_nc(h);

    f32x4 den = (f32x4){0.f, 0.f, 0.f, 0.f};
    f32x4 acc = (f32x4){0.f, 0.f, 0.f, 0.f};
    for (int c = 0; c < nc; ++c) {
        const size_t gbase = (((size_t)h * MAXNC + c) * 512 + g);
        den += *(const f32x4*)(lp + gbase * 4);
        const uint2 pk = *(const uint2*)(Opart + (gbase * 64 + col) * 2);
        acc[0] += __int_as_float(pk.x << 16);
        acc[1] += __int_as_float((int)(pk.x & 0xffff0000u));
        acc[2] += __int_as_float(pk.y << 16);
        acc[3] += __int_as_float((int)(pk.y & 0xffff0000u));
    }
    float* Oh = Om + (size_t)h * S_LEN * D_DIM;
    #pragma unroll
    for (int r = 0; r < 4; ++r)
        Oh[(size_t)(g * 4 + r) * 64 + col] = acc[r] / den[r];
}

extern "C" void kernel_launch(void* const* d_in, const int* in_sizes, int n_in,
                              void* d_out, int out_size, void* d_ws, size_t ws_size,
                              hipStream_t stream) {
    (void)in_sizes; (void)n_in; (void)out_size; (void)ws_size;
    const float* Q = (const float*)d_in[0];
    const float* K = (const float*)d_in[1];
    const float* V = (const float*)d_in[2];
    const void*  M = d_in[3];
    float* O = (float*)d_out;

    char* ws = (char*)d_ws;
    size_t off = 0;
    short* Kswz = (short*)(ws + off); off += (size_t)H_NUM * S_LEN * D_DIM * 2;            // 4 MB
    short* Vswz = (short*)(ws + off); off += (size_t)H_NUM * S_LEN * D_DIM * 2;            // 4 MB
    short* Qbf  = (short*)(ws + off); off += (size_t)H_NUM * S_LEN * D_DIM * 2;            // 4 MB
    float* Bias = (float*)(ws + off); off += (size_t)H_NUM * S_LEN * 4;                    // 128 KB
    unsigned* Opart = (unsigned*)(ws + off); off += (size_t)H_NUM * MAXNC * 512 * 64 * 8;  // 33.5 MB
    float* lp   = (float*)(ws + off); off += (size_t)H_NUM * MAXNC * 512 * 4 * 4;          // 1 MB

    preprocess_kernel<<<dim3(NTILE, H_NUM), 256, 0, stream>>>(Q, K, V, M, Qbf, Kswz, Vswz, Bias);
    attn_main<<<dim3(QB, H_NUM, MAXNC), 256, 0, stream>>>(Qbf, Kswz, Vswz, Bias, O, Opart, lp);
    attn_combine_kernel<<<((H_NUM - HC0) * 512 * 64) / 256, 256, 0, stream>>>(Opart, lp, O);
}

// Round 12
// 97.908 us; speedup vs baseline: 1.0216x; 1.0216x over previous
//
#include <hip/hip_runtime.h>

// ScaledDotProductAttention w/ ALiBi + key padding mask. B=1,H=16,S=2048,D=64 fp32.
// R12 == revert to R9 (best passing: 98.15us). R11's double-buffer cost
// occupancy (4->3 blocks/CU) for no gain -- inter-block wave overlap already
// hides staging latency at ~3 live blocks/CU (matches m99/m100 precedent).
// Structure: 3 dispatches (R7 showed fused-combine __threadfence = per-block
// L2 writeback on non-coherent XCD L2s -> disaster). Carried: bf16 pre-scaled
// Q, bf16 partials, no online max (bias in acc init, exp2 domain), ALiBi
// window cut, weighted chunking (<=4 tiles/blk), global_load_lds staging of
// pre-swizzled bf16 K/V^T, packed-u32 P round-trip, direct O-write for
// single-chunk heads.

constexpr int   S_LEN  = 2048;
constexpr int   D_DIM  = 64;
constexpr int   H_NUM  = 16;
constexpr int   QT     = 128;            // q rows per block (4 waves x 32)
constexpr int   K_TILE = 64;
constexpr int   NTILE  = S_LEN / K_TILE; // 32
constexpr int   MAXNC  = 8;              // max chunks per head (z-dim)
constexpr int   QB     = S_LEN / QT;     // 16
constexpr int   HC0    = 6;              // first multi-chunk head (h0..h5 have nc==1)
constexpr int   PROWSTR= 36;             // dwords per P row (144B, 16B-mult)
constexpr float SCL    = 0.18033688f;    // 0.125 * log2(e)
constexpr float L2E    = 1.44269504f;
constexpr float MASKED = -50000.0f;      // exp2-domain masked-key sentinel -> exp2 = 0
constexpr float CUTOFF = 40.0f;          // log2-units: bias < -40 => key negligible

typedef short bf16x8 __attribute__((ext_vector_type(8)));
typedef short bf16x4 __attribute__((ext_vector_type(4)));
typedef float f32x4  __attribute__((ext_vector_type(4)));

__device__ inline short f2bf(float f) {
    union { float f; unsigned u; } x; x.f = f;
    return (short)((x.u + 0x7fffu + ((x.u >> 16) & 1u)) >> 16);  // RNE
}

__device__ inline unsigned pack2bf(float a, float b) {
#if __has_builtin(__builtin_amdgcn_cvt_pk_bf16_f32)
    auto p = __builtin_amdgcn_cvt_pk_bf16_f32(a, b);
    unsigned u; __builtin_memcpy(&u, &p, 4); return u;
#else
    return (unsigned)(unsigned short)f2bf(a) | ((unsigned)(unsigned short)f2bf(b) << 16);
#endif
}

__device__ inline float fexp2(float x) {
#if __has_builtin(__builtin_amdgcn_exp2f)
    return __builtin_amdgcn_exp2f(x);
#else
    return exp2f(x);
#endif
}

__device__ inline unsigned permb(unsigned hi, unsigned lo, unsigned sel) {
#if __has_builtin(__builtin_amdgcn_perm)
    return __builtin_amdgcn_perm(hi, lo, sel);
#else
    return (sel == 0x05040100u) ? ((lo & 0xffffu) | (hi << 16))
                                : ((lo >> 16) | (hi & 0xffff0000u));
#endif
}

__device__ inline void load_lds16(const void* g, void* l) {
    __builtin_amdgcn_global_load_lds((const __attribute__((address_space(1))) void*)g,
                                     (__attribute__((address_space(3))) void*)l, 16, 0, 0);
}

// first live tile for head h (identical IEEE expression in all kernels)
__device__ inline int head_t0(int h) {
    const float slope_l2e = exp2f(-0.5f * (float)(h + 1)) * L2E;
    const float kmin = 2047.0f - CUTOFF / slope_l2e;
    return kmin <= 0.0f ? 0 : ((int)kmin) >> 6;
}
// chunks for head h: ceil(live_tiles / 4), capped at MAXNC
__device__ inline int head_nc(int h) {
    const int nt = NTILE - head_t0(h);
    const int nc = (nt + 3) >> 2;
    return nc > MAXNC ? MAXNC : nc;
}

// ---- preprocess: Q -> bf16 pre-scaled; K -> bf16 row-chunk-swizzled;
//      V -> bf16 transposed+swizzled; bias (exp2 units, mask folded). ----
__global__ __launch_bounds__(256)
void preprocess_kernel(const float* __restrict__ Qm, const float* __restrict__ Km,
                       const float* __restrict__ Vm, const void* __restrict__ maskp,
                       short* __restrict__ Qbf, short* __restrict__ Kswz,
                       short* __restrict__ Vswz, float* __restrict__ Bias)
{
    __shared__ int mask_is_i32;
    const int tid = threadIdx.x;
    const int kt = blockIdx.x, h = blockIdx.y;

    // Q tile: rows [kt*64, kt*64+64) of head h -> bf16 * SCL, row-major
    {
        const int row = kt * 64 + (tid >> 2);
        const int col = (tid & 3) << 4;
        const float* src = Qm + ((size_t)h * S_LEN + row) * D_DIM + col;
        short* dst = Qbf + ((size_t)h * S_LEN + row) * D_DIM + col;
        #pragma unroll
        for (int j = 0; j < 2; ++j) {
            float4 a = *(const float4*)(src + j * 8);
            float4 b = *(const float4*)(src + j * 8 + 4);
            unsigned u[4] = { pack2bf(a.x * SCL, a.y * SCL), pack2bf(a.z * SCL, a.w * SCL),
                              pack2bf(b.x * SCL, b.y * SCL), pack2bf(b.z * SCL, b.w * SCL) };
            bf16x8 qp; __builtin_memcpy(&qp, u, 16);
            *(bf16x8*)(dst + j * 8) = qp;
        }
    }

    if (kt < head_t0(h)) return;            // dead K/V tile for this head

    const int kbase = kt * K_TILE;
    const size_t tbase = ((size_t)h * S_LEN + kbase) * D_DIM;
    short* Kd = Kswz + ((size_t)h * NTILE + kt) * 4096;
    short* Vd = Vswz + ((size_t)h * NTILE + kt) * 4096;

    // parallel mask-dtype sniff: first wave, one load + ballot
    if (tid < 64) {
        const unsigned v = ((const unsigned*)maskp)[tid];
        const unsigned long long b = __ballot(v <= 1u);
        if (tid == 0) mask_is_i32 = (b == ~0ULL);
    }

    // K: chunk c of row `key` stored at c ^ (key&7)
    #pragma unroll
    for (int it = 0; it < 2; ++it) {
        const int idx = it * 256 + tid;
        const int key = idx >> 3, c = idx & 7;
        const float* src = Km + tbase + key * 64 + c * 8;
        float4 a = *(const float4*)src;
        float4 b = *(const float4*)(src + 4);
        unsigned u[4] = { pack2bf(a.x, a.y), pack2bf(a.z, a.w),
                          pack2bf(b.x, b.y), pack2bf(b.z, b.w) };
        bf16x8 kp; __builtin_memcpy(&kp, u, 16);
        *(bf16x8*)(Kd + key * 64 + ((c ^ (key & 7)) << 3)) = kp;
    }

    // V: 4x4 register transpose; row d, key-chunk (key>>3)^(d&7)
    {
        const int db = tid >> 4, kb = tid & 15;
        const int d4 = db * 4, key4 = kb * 4;
        float4 vv[4];
        #pragma unroll
        for (int j = 0; j < 4; ++j)
            vv[j] = *(const float4*)(Vm + tbase + (key4 + j) * 64 + d4);
        const float* vp = (const float*)vv;
        #pragma unroll
        for (int jj = 0; jj < 4; ++jj) {
            const int d = d4 + jj;
            bf16x4 ov;
            ov[0] = f2bf(vp[0 * 4 + jj]); ov[1] = f2bf(vp[1 * 4 + jj]);
            ov[2] = f2bf(vp[2 * 4 + jj]); ov[3] = f2bf(vp[3 * 4 + jj]);
            *(bf16x4*)(Vd + d * 64 + (((key4 >> 3) ^ (d & 7)) << 3) + (key4 & 7)) = ov;
        }
    }
    __syncthreads();
    if (tid < K_TILE) {
        const int key = kbase + tid;
        const int mv = mask_is_i32 ? ((const int*)maskp)[key]
                                   : (int)((const unsigned char*)maskp)[key];
        const float slope_l2e = exp2f(-0.5f * (float)(h + 1)) * L2E;
        Bias[h * S_LEN + key] = mv ? slope_l2e * (float)(key - (S_LEN - 1)) : MASKED;
    }
}

// ---- main flash kernel (no max pass; bias in accumulator init) ----
__global__ __launch_bounds__(256, 4)
void attn_main(const short* __restrict__ Qbf, const short* __restrict__ Kswz,
               const short* __restrict__ Vswz, const float* __restrict__ Bias,
               float* __restrict__ Om, unsigned* __restrict__ Opart,
               float* __restrict__ lp)
{
    __shared__ short    k_lds[4096];
    __shared__ short    v_lds[4096];
    __shared__ float    bm_lds[64];
    __shared__ unsigned p_lds[4][32 * PROWSTR];

    const int tid = threadIdx.x;
    const int wave = tid >> 6, lane = tid & 63;
    const int l16 = lane & 15, quad = lane >> 4;
    const int h = blockIdx.y, qblk = blockIdx.x, c = blockIdx.z;

    const int nc = head_nc(h);
    if (c >= nc) return;                      // dead chunk for this head
    const int t0 = head_t0(h);
    const int nt = NTILE - t0;
    const int tstart = t0 + (c * nt) / nc;
    const int tend   = t0 + ((c + 1) * nt) / nc;   // <= tstart+4

    const unsigned psel = (quad < 2) ? 0x05040100u : 0x07060302u;

    // Q A-frags (already bf16, pre-scaled): 16B contiguous loads
    bf16x8 qfrag[2][2];
    {
        const short* Qh = Qbf + (size_t)h * S_LEN * D_DIM;
        #pragma unroll
        for (int s = 0; s < 2; ++s) {
            const int qrow = qblk * QT + wave * 32 + s * 16 + l16;
            #pragma unroll
            for (int t = 0; t < 2; ++t)
                qfrag[s][t] = *(const bf16x8*)(Qh + (size_t)qrow * D_DIM + t * 32 + quad * 8);
        }
    }

    bf16x8 onesv;
    #pragma unroll
    for (int i = 0; i < 8; ++i) onesv[i] = (short)0x3F80;  // bf16 1.0

    f32x4 o_frag[2][4], l4[2];
    #pragma unroll
    for (int s = 0; s < 2; ++s) {
        #pragma unroll
        for (int cc = 0; cc < 4; ++cc) o_frag[s][cc] = (f32x4){0.f, 0.f, 0.f, 0.f};
        l4[s] = (f32x4){0.f, 0.f, 0.f, 0.f};
    }

    const short* Kh = Kswz + (size_t)h * NTILE * 4096;
    const short* Vh = Vswz + (size_t)h * NTILE * 4096;
    const float* Bh = Bias + h * S_LEN;
    unsigned* pw = p_lds[wave];
    const int swz = l16 & 7;

    for (int kt = tstart; kt < tend; ++kt) {
        __syncthreads();
        {
            const char* kg = (const char*)(Kh + (size_t)kt * 4096);
            const char* vg = (const char*)(Vh + (size_t)kt * 4096);
            char* kl = (char*)k_lds + wave * 2048;
            char* vl = (char*)v_lds + wave * 2048;
            const int go = wave * 2048 + lane * 16;
            load_lds16(kg + go,        kl);
            load_lds16(kg + go + 1024, kl + 1024);
            load_lds16(vg + go,        vl);
            load_lds16(vg + go + 1024, vl + 1024);
        }
        if (tid < 16) {
            float4 b4 = *(const float4*)(Bh + kt * K_TILE + tid * 4);
            *(float4*)&bm_lds[tid * 4] = b4;
        }
        __syncthreads();

        // S(+bias) = bias_init + Q K^T
        f32x4 sv[2][4];
        #pragma unroll
        for (int cc = 0; cc < 4; ++cc) {
            const float b = bm_lds[cc * 16 + l16];
            const f32x4 binit = (f32x4){b, b, b, b};
            sv[0][cc] = binit;
            sv[1][cc] = binit;
            #pragma unroll
            for (int t = 0; t < 2; ++t) {
                bf16x8 bfrag = *(const bf16x8*)&k_lds[(cc * 16 + l16) * 64 + (((t * 4 + quad) ^ swz) << 3)];
                sv[0][cc] = __builtin_amdgcn_mfma_f32_16x16x32_bf16(qfrag[0][t], bfrag, sv[0][cc], 0, 0, 0);
                sv[1][cc] = __builtin_amdgcn_mfma_f32_16x16x32_bf16(qfrag[1][t], bfrag, sv[1][cc], 0, 0, 0);
            }
        }

        // p = exp2(s)
        #pragma unroll
        for (int s = 0; s < 2; ++s) {
            #pragma unroll
            for (int r = 0; r < 4; ++r) {
                const float p0 = fexp2(sv[s][0][r]);
                const float p1 = fexp2(sv[s][1][r]);
                const float p2 = fexp2(sv[s][2][r]);
                const float p3 = fexp2(sv[s][3][r]);
                unsigned* pp = &pw[(s * 16 + quad * 4 + r) * PROWSTR + l16];
                pp[0]  = pack2bf(p0, p1);
                pp[16] = pack2bf(p2, p3);
            }
        }

        // O += P V ; l += P * ones
        #pragma unroll
        for (int t2 = 0; t2 < 2; ++t2) {
            bf16x8 pfrag[2];
            #pragma unroll
            for (int s = 0; s < 2; ++s) {
                const unsigned* pr = &pw[(s * 16 + l16) * PROWSTR + t2 * 16 + (quad & 1) * 8];
                uint4 w0 = *(const uint4*)(pr);
                uint4 w1 = *(const uint4*)(pr + 4);
                unsigned pf[4];
                pf[0] = permb(w0.y, w0.x, psel);
                pf[1] = permb(w0.w, w0.z, psel);
                pf[2] = permb(w1.y, w1.x, psel);
                pf[3] = permb(w1.w, w1.z, psel);
                __builtin_memcpy(&pfrag[s], pf, 16);
            }
            #pragma unroll
            for (int c2 = 0; c2 < 4; ++c2) {
                bf16x8 vfrag = *(const bf16x8*)&v_lds[(c2 * 16 + l16) * 64 + (((t2 * 4 + quad) ^ swz) << 3)];
                o_frag[0][c2] = __builtin_amdgcn_mfma_f32_16x16x32_bf16(pfrag[0], vfrag, o_frag[0][c2], 0, 0, 0);
                o_frag[1][c2] = __builtin_amdgcn_mfma_f32_16x16x32_bf16(pfrag[1], vfrag, o_frag[1][c2], 0, 0, 0);
            }
            l4[0] = __builtin_amdgcn_mfma_f32_16x16x32_bf16(pfrag[0], onesv, l4[0], 0, 0, 0);
            l4[1] = __builtin_amdgcn_mfma_f32_16x16x32_bf16(pfrag[1], onesv, l4[1], 0, 0, 0);
        }
    }

    if (nc == 1) {
        // sole chunk: write normalized O directly, skip combine
        float* Oh = Om + (size_t)h * S_LEN * D_DIM;
        const int qrow0 = qblk * QT + wave * 32;
        #pragma unroll
        for (int s = 0; s < 2; ++s) {
            #pragma unroll
            for (int r = 0; r < 4; ++r) {
                const float inv = 1.0f / l4[s][r];
                const int row = qrow0 + s * 16 + quad * 4 + r;
                float* dst = Oh + (size_t)row * D_DIM + l16;
                dst[0]  = o_frag[s][0][r] * inv;
                dst[16] = o_frag[s][1][r] * inv;
                dst[32] = o_frag[s][2][r] * inv;
                dst[48] = o_frag[s][3][r] * inv;
            }
        }
        return;
    }

    // bf16 partial + fp32 l per row-group; slot = h*MAXNC + c
    #pragma unroll
    for (int s = 0; s < 2; ++s) {
        const int g = qblk * 32 + wave * 8 + s * 4 + quad;
        const size_t gbase = (((size_t)h * MAXNC + c) * 512 + g);
        #pragma unroll
        for (int c2 = 0; c2 < 4; ++c2) {
            uint2 pk;
            pk.x = pack2bf(o_frag[s][c2][0], o_frag[s][c2][1]);
            pk.y = pack2bf(o_frag[s][c2][2], o_frag[s][c2][3]);
            *(uint2*)(Opart + (gbase * 64 + c2 * 16 + l16) * 2) = pk;
        }
        if (l16 == 0) *(f32x4*)(lp + gbase * 4) = l4[s];
    }
}

__global__ __launch_bounds__(256)
void attn_combine_kernel(const unsigned* __restrict__ Opart, const float* __restrict__ lp,
                         float* __restrict__ Om)
{
    const int t   = blockIdx.x * 256 + threadIdx.x;   // (H-HC0)*512*64 threads
    const int col = t & 63;
    const int g   = (t >> 6) & 511;
    const int h   = HC0 + (t >> 15);

    const int nc = head_nc(h);

    f32x4 den = (f32x4){0.f, 0.f, 0.f, 0.f};
    f32x4 acc = (f32x4){0.f, 0.f, 0.f, 0.f};
    for (int c = 0; c < nc; ++c) {
        const size_t gbase = (((size_t)h * MAXNC + c) * 512 + g);
        den += *(const f32x4*)(lp + gbase * 4);
        const uint2 pk = *(const uint2*)(Opart + (gbase * 64 + col) * 2);
        acc[0] += __int_as_float(pk.x << 16);
        acc[1] += __int_as_float((int)(pk.x & 0xffff0000u));
        acc[2] += __int_as_float(pk.y << 16);
        acc[3] += __int_as_float((int)(pk.y & 0xffff0000u));
    }
    float* Oh = Om + (size_t)h * S_LEN * D_DIM;
    #pragma unroll
    for (int r = 0; r < 4; ++r)
        Oh[(size_t)(g * 4 + r) * 64 + col] = acc[r] / den[r];
}

extern "C" void kernel_launch(void* const* d_in, const int* in_sizes, int n_in,
                              void* d_out, int out_size, void* d_ws, size_t ws_size,
                              hipStream_t stream) {
    (void)in_sizes; (void)n_in; (void)out_size; (void)ws_size;
    const float* Q = (const float*)d_in[0];
    const float* K = (const float*)d_in[1];
    const float* V = (const float*)d_in[2];
    const void*  M = d_in[3];
    float* O = (float*)d_out;

    char* ws = (char*)d_ws;
    size_t off = 0;
    short* Kswz = (short*)(ws + off); off += (size_t)H_NUM * S_LEN * D_DIM * 2;            // 4 MB
    short* Vswz = (short*)(ws + off); off += (size_t)H_NUM * S_LEN * D_DIM * 2;            // 4 MB
    short* Qbf  = (short*)(ws + off); off += (size_t)H_NUM * S_LEN * D_DIM * 2;            // 4 MB
    float* Bias = (float*)(ws + off); off += (size_t)H_NUM * S_LEN * 4;                    // 128 KB
    unsigned* Opart = (unsigned*)(ws + off); off += (size_t)H_NUM * MAXNC * 512 * 64 * 8;  // 33.5 MB
    float* lp   = (float*)(ws + off); off += (size_t)H_NUM * MAXNC * 512 * 4 * 4;          // 1 MB

    preprocess_kernel<<<dim3(NTILE, H_NUM), 256, 0, stream>>>(Q, K, V, M, Qbf, Kswz, Vswz, Bias);
    attn_main<<<dim3(QB, H_NUM, MAXNC), 256, 0, stream>>>(Qbf, Kswz, Vswz, Bias, O, Opart, lp);
    attn_combine_kernel<<<((H_NUM - HC0) * 512 * 64) / 256, 256, 0, stream>>>(Opart, lp, O);
}